// Round 1
// baseline (1525.616 us; speedup 1.0000x reference)
//
#include <hip/hip_runtime.h>
#include <cstdint>

#define CH 64
#define POOL_NODES 256

// ---------------- preprocessing: degree, CSR-by-dst ----------------
__global__ __launch_bounds__(256) void k_hist(const int* __restrict__ src, const int* __restrict__ dst,
                                              int* __restrict__ deg_src, int* __restrict__ cnt_dst, int E) {
  int e = blockIdx.x * 256 + threadIdx.x;
  if (e < E) {
    atomicAdd(&deg_src[src[e]], 1);
    atomicAdd(&cnt_dst[dst[e]], 1);
  }
}

__global__ __launch_bounds__(256) void k_neg_inv(const int* __restrict__ deg, float* __restrict__ neg_inv, int n) {
  int i = blockIdx.x * 256 + threadIdx.x;
  if (i < n) {
    int d = deg[i];
    neg_inv[i] = d > 0 ? (-1.0f / (float)d) : 0.0f;   // ew = -1/deg[src]
  }
}

// exclusive scan of cnt (1024 elems/block) -> row_ptr, block totals -> bsum
__global__ __launch_bounds__(256) void k_scan_local(const int* __restrict__ cnt, int* __restrict__ row_ptr,
                                                    int* __restrict__ bsum, int n) {
  __shared__ int s[256];
  int t = threadIdx.x;
  int base = blockIdx.x * 1024 + t * 4;
  int v0 = (base + 0 < n) ? cnt[base + 0] : 0;
  int v1 = (base + 1 < n) ? cnt[base + 1] : 0;
  int v2 = (base + 2 < n) ? cnt[base + 2] : 0;
  int v3 = (base + 3 < n) ? cnt[base + 3] : 0;
  int sum = v0 + v1 + v2 + v3;
  s[t] = sum;
  __syncthreads();
  for (int off = 1; off < 256; off <<= 1) {
    int x = (t >= off) ? s[t - off] : 0;
    __syncthreads();
    s[t] += x;
    __syncthreads();
  }
  int excl = s[t] - sum;
  if (base + 0 < n) row_ptr[base + 0] = excl;  excl += v0;
  if (base + 1 < n) row_ptr[base + 1] = excl;  excl += v1;
  if (base + 2 < n) row_ptr[base + 2] = excl;  excl += v2;
  if (base + 3 < n) row_ptr[base + 3] = excl;
  if (t == 255) bsum[blockIdx.x] = s[255];
}

__global__ void k_scan_bsums(int* bsum, int nb) {
  if (blockIdx.x == 0 && threadIdx.x == 0) {
    int run = 0;
    for (int i = 0; i < nb; ++i) { int v = bsum[i]; bsum[i] = run; run += v; }
  }
}

__global__ __launch_bounds__(256) void k_scan_add(int* __restrict__ row_ptr, const int* __restrict__ bsum,
                                                  int* __restrict__ cursor, int n, int E) {
  int i = blockIdx.x * 256 + threadIdx.x;
  if (i < n) {
    int v = row_ptr[i] + bsum[i >> 10];
    row_ptr[i] = v;
    cursor[i] = v;
  } else if (i == n) {
    row_ptr[n] = E;
  }
}

// pack (src, ew) per edge, sorted by dst via atomic cursors
__global__ __launch_bounds__(256) void k_scatter(const int* __restrict__ src, const int* __restrict__ dst,
                                                 const float* __restrict__ neg_inv, int* __restrict__ cursor,
                                                 int2* __restrict__ erec, int E) {
  int e = blockIdx.x * 256 + threadIdx.x;
  if (e < E) {
    int d = dst[e];
    int p = atomicAdd(&cursor[d], 1);
    int s = src[e];
    erec[p] = make_int2(s, __float_as_int(neg_inv[s]));
  }
}

// ---------------- sparse propagation: one wave per node, lane = channel ----------------
// mode 1: t_out = prop(t_in);  mode 2: t_out = 2*prop(t_in) - t_sub
__global__ __launch_bounds__(256) void k_prop(const int* __restrict__ row_ptr, const int2* __restrict__ erec,
                                              const float* __restrict__ t_in, const float* __restrict__ t_sub,
                                              float* __restrict__ t_out, int n, int mode) {
  int tid = threadIdx.x;
  int lane = tid & 63;
  int node = blockIdx.x * 4 + (tid >> 6);
  if (node >= n) return;
  int beg = row_ptr[node], end = row_ptr[node + 1];
  float s = 0.f;
  for (int e = beg; e < end; ++e) {
    int2 r = erec[e];                       // broadcast 8B load
    s += __int_as_float(r.y) * t_in[r.x * CH + lane];  // coalesced 256B gather
  }
  float val = (mode == 1) ? s : (2.0f * s - t_sub[node * CH + lane]);
  t_out[node * CH + lane] = val;
}

// ---------------- fused out = selu(sum_k Mk@W[k] + b) ----------------
// lane = node (64-node tile per wave), 64-register accumulator, XOR-swizzled LDS tiles.
__global__ __launch_bounds__(256) void k_matmul5(
    const float* __restrict__ M0, const float* __restrict__ M1, const float* __restrict__ M2,
    const float* __restrict__ M3, const float* __restrict__ M4,
    const float* __restrict__ W, const float* __restrict__ bias,
    float* __restrict__ outp, int n) {
  __shared__ float S4[4][CH * CH];          // 64 KB, per-wave private 16KB tiles
  int tid = threadIdx.x;
  int wave = tid >> 6, lane = tid & 63;
  float* S = S4[wave];
  int node0 = (blockIdx.x * 4 + wave) * 64;
  float acc[64];
#pragma unroll
  for (int j = 0; j < 64; ++j) acc[j] = 0.f;
  const float* mats[5] = {M0, M1, M2, M3, M4};
#pragma unroll
  for (int m = 0; m < 5; ++m) {
    const float* __restrict__ T = mats[m];
    // stage tile (coalesced float4 loads; swizzle col^(row&31) to kill bank conflicts)
#pragma unroll
    for (int it = 0; it < 16; ++it) {
      int flat4 = it * 64 + lane;           // 0..1023
      int r = flat4 >> 4;                   // 0..63
      int c4 = (flat4 & 15) << 2;
      int row = node0 + r;
      float4 v;
      if (row < n) v = *(const float4*)(T + (size_t)row * CH + c4);
      else v = make_float4(0.f, 0.f, 0.f, 0.f);
      int k = r & 31;
      S[r * 64 + ((c4 + 0) ^ k)] = v.x;
      S[r * 64 + ((c4 + 1) ^ k)] = v.y;
      S[r * 64 + ((c4 + 2) ^ k)] = v.z;
      S[r * 64 + ((c4 + 3) ^ k)] = v.w;
    }
    const float* __restrict__ Wm = W + m * CH * CH;
#pragma unroll 2
    for (int c = 0; c < 64; ++c) {
      float tc = S[lane * 64 + (c ^ (lane & 31))];   // 2 lanes/bank -> conflict-free
      const float4* __restrict__ W4 = (const float4*)(Wm + c * 64);  // uniform -> s_load
#pragma unroll
      for (int j4 = 0; j4 < 16; ++j4) {
        float4 w = W4[j4];
        acc[4 * j4 + 0] = fmaf(tc, w.x, acc[4 * j4 + 0]);
        acc[4 * j4 + 1] = fmaf(tc, w.y, acc[4 * j4 + 1]);
        acc[4 * j4 + 2] = fmaf(tc, w.z, acc[4 * j4 + 2]);
        acc[4 * j4 + 3] = fmaf(tc, w.w, acc[4 * j4 + 3]);
      }
    }
  }
  // epilogue: bias + selu, bounce via LDS for coalesced store
  const float sc = 1.0507009873554805f, al = 1.6732632423543773f;
#pragma unroll
  for (int j = 0; j < 64; ++j) {
    float v = acc[j] + bias[j];
    v = (v > 0.f) ? (sc * v) : (sc * al * (expf(v) - 1.f));
    S[lane * 64 + (j ^ (lane & 31))] = v;
  }
#pragma unroll
  for (int it = 0; it < 64; ++it) {
    int row = node0 + it;
    if (row < n) outp[(size_t)row * CH + lane] = S[it * 64 + (lane ^ (it & 31))];
  }
}

// ---------------- pool (batch sorted -> run-length accumulate) + fc ----------------
__global__ __launch_bounds__(256) void k_pool(const float* __restrict__ h, const int* __restrict__ batch,
                                              float* __restrict__ g, int n) {
  int c = threadIdx.x & 63;
  int rg = threadIdx.x >> 6;
  int start = blockIdx.x * POOL_NODES;
  float cur = 0.f;
  int curg = -1;
  for (int j = rg; j < POOL_NODES; j += 4) {
    int i = start + j;
    if (i >= n) break;
    int b = batch[i];
    if (b != curg) {
      if (curg >= 0) atomicAdd(&g[curg * CH + c], cur);
      curg = b;
      cur = 0.f;
    }
    cur += h[(size_t)i * CH + c];
  }
  if (curg >= 0) atomicAdd(&g[curg * CH + c], cur);
}

__global__ __launch_bounds__(256) void k_fc(const float* __restrict__ g, const float* __restrict__ Wfc,
                                            const float* __restrict__ bfc, float* __restrict__ outp,
                                            int ng, int oc) {
  int i = blockIdx.x * 256 + threadIdx.x;
  if (i < ng * oc) {
    int gi = i / oc, o = i - gi * oc;
    float s = bfc[o];
    for (int ci = 0; ci < CH; ++ci) s += g[gi * CH + ci] * Wfc[ci * oc + o];
    outp[i] = s;
  }
}

extern "C" void kernel_launch(void* const* d_in, const int* in_sizes, int n_in,
                              void* d_out, int out_size, void* d_ws, size_t ws_size,
                              hipStream_t stream) {
  const float* x   = (const float*)d_in[0];
  const int* eidx  = (const int*)d_in[1];
  const int* batch = (const int*)d_in[2];
  const float* W1  = (const float*)d_in[3];
  const float* b1  = (const float*)d_in[4];
  const float* W2  = (const float*)d_in[5];
  const float* b2  = (const float*)d_in[6];
  const float* Wfc = (const float*)d_in[7];
  const float* bfc = (const float*)d_in[8];
  float* out = (float*)d_out;

  const int n  = in_sizes[0] / CH;        // 100000
  const int E  = in_sizes[1] / 2;         // 1250000
  const int OC = in_sizes[8];             // 10
  const int NG = out_size / OC;           // 64

  const int* src = eidx;
  const int* dst = eidx + E;

  size_t off = 0;
  char* base = (char*)d_ws;
  auto alloc = [&](size_t bytes) -> void* {
    size_t cur = (off + 255) & ~(size_t)255;
    off = cur + bytes;
    return (void*)(base + cur);
  };
  int*   deg_src = (int*)alloc((size_t)n * 4);
  int*   cnt_dst = (int*)alloc((size_t)n * 4);
  float* neg_inv = (float*)alloc((size_t)n * 4);
  int*   row_ptr = (int*)alloc((size_t)(n + 1) * 4);
  int*   cursor  = (int*)alloc((size_t)n * 4);
  const int nb   = (n + 1023) / 1024;
  int*   bsum    = (int*)alloc((size_t)nb * 4);
  int2*  erec    = (int2*)alloc((size_t)E * 8);
  const size_t tbytes = (size_t)n * CH * 4;
  float* T1 = (float*)alloc(tbytes);
  float* T2 = (float*)alloc(tbytes);
  float* T3 = (float*)alloc(tbytes);
  float* T4 = (float*)alloc(tbytes);
  float* H  = (float*)alloc(tbytes);
  float* g  = (float*)alloc((size_t)NG * CH * 4);
  if (off > ws_size) return;  // workspace too small -> fail loudly (zeros out)

  hipMemsetAsync(deg_src, 0, (size_t)n * 4, stream);
  hipMemsetAsync(cnt_dst, 0, (size_t)n * 4, stream);
  hipMemsetAsync(g, 0, (size_t)NG * CH * 4, stream);

  const int eb  = (E + 255) / 256;
  const int nbk = (n + 255) / 256;
  k_hist<<<eb, 256, 0, stream>>>(src, dst, deg_src, cnt_dst, E);
  k_neg_inv<<<nbk, 256, 0, stream>>>(deg_src, neg_inv, n);
  k_scan_local<<<nb, 256, 0, stream>>>(cnt_dst, row_ptr, bsum, n);
  k_scan_bsums<<<1, 64, 0, stream>>>(bsum, nb);
  k_scan_add<<<(n + 1 + 255) / 256, 256, 0, stream>>>(row_ptr, bsum, cursor, n, E);
  k_scatter<<<eb, 256, 0, stream>>>(src, dst, neg_inv, cursor, erec, E);

  const int pb = (n + 3) / 4;
  const int mb = (n + 255) / 256;
  // layer 1: Tx rotation T1..T4, then fused matmul+bias+selu -> H
  k_prop<<<pb, 256, 0, stream>>>(row_ptr, erec, x,  nullptr, T1, n, 1);
  k_prop<<<pb, 256, 0, stream>>>(row_ptr, erec, T1, x,  T2, n, 2);
  k_prop<<<pb, 256, 0, stream>>>(row_ptr, erec, T2, T1, T3, n, 2);
  k_prop<<<pb, 256, 0, stream>>>(row_ptr, erec, T3, T2, T4, n, 2);
  k_matmul5<<<mb, 256, 0, stream>>>(x, T1, T2, T3, T4, W1, b1, H, n);
  // layer 2 (matmul writes H in place: tiling is row-local, all reads precede writes)
  k_prop<<<pb, 256, 0, stream>>>(row_ptr, erec, H,  nullptr, T1, n, 1);
  k_prop<<<pb, 256, 0, stream>>>(row_ptr, erec, T1, H,  T2, n, 2);
  k_prop<<<pb, 256, 0, stream>>>(row_ptr, erec, T2, T1, T3, n, 2);
  k_prop<<<pb, 256, 0, stream>>>(row_ptr, erec, T3, T2, T4, n, 2);
  k_matmul5<<<mb, 256, 0, stream>>>(H, T1, T2, T3, T4, W2, b2, H, n);
  // pool + fc
  k_pool<<<(n + POOL_NODES - 1) / POOL_NODES, 256, 0, stream>>>(H, batch, g, n);
  k_fc<<<(NG * OC + 255) / 256, 256, 0, stream>>>(g, Wfc, bfc, out, NG, OC);
}

// Round 2
// 1293.677 us; speedup vs baseline: 1.1793x; 1.1793x over previous
//
#include <hip/hip_runtime.h>
#include <cstdint>

#define CH 64
#define POOL_NODES 256

typedef __attribute__((ext_vector_type(8))) short bf16x8;
typedef __attribute__((ext_vector_type(8))) unsigned short u16x8;
typedef __attribute__((ext_vector_type(4))) float f32x4;

__device__ __forceinline__ unsigned short f2bf(float x) {
  unsigned u = __float_as_uint(x);
  u += 0x7FFF + ((u >> 16) & 1);          // round-to-nearest-even
  return (unsigned short)(u >> 16);
}

// ---------------- preprocessing: degree, CSR-by-dst ----------------
__global__ __launch_bounds__(256) void k_hist(const int* __restrict__ src, const int* __restrict__ dst,
                                              int* __restrict__ deg_src, int* __restrict__ cnt_dst, int E) {
  int e = blockIdx.x * 256 + threadIdx.x;
  if (e < E) {
    atomicAdd(&deg_src[src[e]], 1);
    atomicAdd(&cnt_dst[dst[e]], 1);
  }
}

__global__ __launch_bounds__(256) void k_neg_inv(const int* __restrict__ deg, float* __restrict__ neg_inv, int n) {
  int i = blockIdx.x * 256 + threadIdx.x;
  if (i < n) {
    int d = deg[i];
    neg_inv[i] = d > 0 ? (-1.0f / (float)d) : 0.0f;   // ew = -1/deg[src]
  }
}

// exclusive scan of cnt (1024 elems/block) -> row_ptr, block totals -> bsum
__global__ __launch_bounds__(256) void k_scan_local(const int* __restrict__ cnt, int* __restrict__ row_ptr,
                                                    int* __restrict__ bsum, int n) {
  __shared__ int s[256];
  int t = threadIdx.x;
  int base = blockIdx.x * 1024 + t * 4;
  int v0 = (base + 0 < n) ? cnt[base + 0] : 0;
  int v1 = (base + 1 < n) ? cnt[base + 1] : 0;
  int v2 = (base + 2 < n) ? cnt[base + 2] : 0;
  int v3 = (base + 3 < n) ? cnt[base + 3] : 0;
  int sum = v0 + v1 + v2 + v3;
  s[t] = sum;
  __syncthreads();
  for (int off = 1; off < 256; off <<= 1) {
    int x = (t >= off) ? s[t - off] : 0;
    __syncthreads();
    s[t] += x;
    __syncthreads();
  }
  int excl = s[t] - sum;
  if (base + 0 < n) row_ptr[base + 0] = excl;  excl += v0;
  if (base + 1 < n) row_ptr[base + 1] = excl;  excl += v1;
  if (base + 2 < n) row_ptr[base + 2] = excl;  excl += v2;
  if (base + 3 < n) row_ptr[base + 3] = excl;
  if (t == 255) bsum[blockIdx.x] = s[255];
}

// parallel exclusive scan of the (<=128) block sums — replaces serial 1-thread loop
__global__ __launch_bounds__(128) void k_scan_bsums(int* bsum, int nb) {
  __shared__ int s[128];
  int t = threadIdx.x;
  int v = (t < nb) ? bsum[t] : 0;
  s[t] = v;
  __syncthreads();
  for (int off = 1; off < 128; off <<= 1) {
    int x = (t >= off) ? s[t - off] : 0;
    __syncthreads();
    s[t] += x;
    __syncthreads();
  }
  if (t < nb) bsum[t] = s[t] - v;   // exclusive
}

__global__ __launch_bounds__(256) void k_scan_add(int* __restrict__ row_ptr, const int* __restrict__ bsum,
                                                  int* __restrict__ cursor, int n, int E) {
  int i = blockIdx.x * 256 + threadIdx.x;
  if (i < n) {
    int v = row_ptr[i] + bsum[i >> 10];
    row_ptr[i] = v;
    cursor[i] = v;
  } else if (i == n) {
    row_ptr[n] = E;
  }
}

// pack (src, ew) per edge, sorted by dst via atomic cursors
__global__ __launch_bounds__(256) void k_scatter(const int* __restrict__ src, const int* __restrict__ dst,
                                                 const float* __restrict__ neg_inv, int* __restrict__ cursor,
                                                 int2* __restrict__ erec, int E) {
  int e = blockIdx.x * 256 + threadIdx.x;
  if (e < E) {
    int d = dst[e];
    int p = atomicAdd(&cursor[d], 1);
    int s = src[e];
    erec[p] = make_int2(s, __float_as_int(neg_inv[s]));
  }
}

// ---------------- sparse propagation: one wave per node, lane = channel ----------------
// mode 1: t_out = prop(t_in);  mode 2: t_out = 2*prop(t_in) - t_sub
__global__ __launch_bounds__(256) void k_prop(const int* __restrict__ row_ptr, const int2* __restrict__ erec,
                                              const float* __restrict__ t_in, const float* __restrict__ t_sub,
                                              float* __restrict__ t_out, int n, int mode) {
  int tid = threadIdx.x;
  int lane = tid & 63;
  int node = blockIdx.x * 4 + (tid >> 6);
  if (node >= n) return;
  int beg = row_ptr[node], end = row_ptr[node + 1];
  float s = 0.f;
  for (int e = beg; e < end; ++e) {
    int2 r = erec[e];                       // broadcast 8B load
    s += __int_as_float(r.y) * t_in[r.x * CH + lane];  // coalesced 256B gather
  }
  float val = (mode == 1) ? s : (2.0f * s - t_sub[node * CH + lane]);
  t_out[node * CH + lane] = val;
}

// ---------------- W transpose + bf16 convert: Wt[j*320 + k] = bf16(W[k*64 + j]) ----------------
__global__ __launch_bounds__(256) void k_prepW(const float* __restrict__ W, unsigned short* __restrict__ Wt) {
  int o = blockIdx.x * 256 + threadIdx.x;  // o = j*320 + k
  if (o < 64 * 320) {
    int j = o / 320, k = o - j * 320;
    Wt[o] = f2bf(W[k * 64 + j]);
  }
}

// ---------------- fused out = selu([M0|..|M4] @ stackedW + b), bf16 MFMA ----------------
// Block: 64 rows x 64 cols, K=320. A staged fp32->bf16 into 40KB swizzled LDS;
// B fragments read straight from L2 (Wt is 40KB, whole-grid resident).
__global__ __launch_bounds__(256) void k_gemm5(
    const float* __restrict__ M0, const float* __restrict__ M1, const float* __restrict__ M2,
    const float* __restrict__ M3, const float* __restrict__ M4,
    const unsigned short* __restrict__ Wt, const float* __restrict__ bias,
    float* __restrict__ outp, int n) {
  __shared__ unsigned short lds[64 * 320];  // 40KB, A tile, 16B-chunk XOR swizzle
  const int t = threadIdx.x;
  const int lane = t & 63, wave = t >> 6;
  const int node0 = blockIdx.x * 64;
  const float* mats[5] = {M0, M1, M2, M3, M4};
  // ---- stage A ----
#pragma unroll
  for (int m = 0; m < 5; ++m) {
    const float* __restrict__ T = mats[m];
#pragma unroll
    for (int i = 0; i < 2; ++i) {
      int row = i * 32 + (t >> 3);          // 0..63
      int cc = t & 7;                       // 8-float chunk within this mat
      int ca = m * 8 + cc;                  // 16B chunk index within 320-col row
      float4 v0, v1;
      if (node0 + row < n) {
        const float4* p = (const float4*)(T + (size_t)(node0 + row) * CH + cc * 8);
        v0 = p[0]; v1 = p[1];
      } else {
        v0 = make_float4(0.f, 0.f, 0.f, 0.f); v1 = v0;
      }
      u16x8 w;
      w[0] = f2bf(v0.x); w[1] = f2bf(v0.y); w[2] = f2bf(v0.z); w[3] = f2bf(v0.w);
      w[4] = f2bf(v1.x); w[5] = f2bf(v1.y); w[6] = f2bf(v1.z); w[7] = f2bf(v1.w);
      *(u16x8*)(&lds[row * 320 + ((ca ^ (row & 7)) << 3)]) = w;
    }
  }
  __syncthreads();
  // ---- MFMA: wave (wr,wc) computes rows wr*32..+31, cols wc*32..+31 ----
  const int wr = wave >> 1, wc = wave & 1;
  const int g = lane >> 4, r16 = lane & 15;
  const int rowA0 = wr * 32 + r16, rowA1 = rowA0 + 16;
  const int colB0 = wc * 32 + r16, colB1 = colB0 + 16;
  f32x4 acc00 = {}, acc01 = {}, acc10 = {}, acc11 = {};
#pragma unroll 2
  for (int kk = 0; kk < 10; ++kk) {
    int ca = kk * 4 + g;
    bf16x8 a0 = *(const bf16x8*)(&lds[rowA0 * 320 + ((ca ^ (rowA0 & 7)) << 3)]);
    bf16x8 a1 = *(const bf16x8*)(&lds[rowA1 * 320 + ((ca ^ (rowA1 & 7)) << 3)]);
    bf16x8 b0 = *(const bf16x8*)(Wt + colB0 * 320 + kk * 32 + g * 8);
    bf16x8 b1 = *(const bf16x8*)(Wt + colB1 * 320 + kk * 32 + g * 8);
    acc00 = __builtin_amdgcn_mfma_f32_16x16x32_bf16(a0, b0, acc00, 0, 0, 0);
    acc01 = __builtin_amdgcn_mfma_f32_16x16x32_bf16(a0, b1, acc01, 0, 0, 0);
    acc10 = __builtin_amdgcn_mfma_f32_16x16x32_bf16(a1, b0, acc10, 0, 0, 0);
    acc11 = __builtin_amdgcn_mfma_f32_16x16x32_bf16(a1, b1, acc11, 0, 0, 0);
  }
  // ---- epilogue: bias + selu + store (C/D: col=lane&15, row=4*(lane>>4)+reg) ----
  const float sc = 1.0507009873554805f, al = 1.6732632423543773f;
  const f32x4 accs[2][2] = {{acc00, acc01}, {acc10, acc11}};
#pragma unroll
  for (int i = 0; i < 2; ++i) {
#pragma unroll
    for (int j = 0; j < 2; ++j) {
      int col = wc * 32 + j * 16 + r16;
      float bv = bias[col];
#pragma unroll
      for (int rr = 0; rr < 4; ++rr) {
        int row = node0 + wr * 32 + i * 16 + g * 4 + rr;
        if (row < n) {
          float v = accs[i][j][rr] + bv;
          v = (v > 0.f) ? (sc * v) : (sc * al * (expf(v) - 1.f));
          outp[(size_t)row * CH + col] = v;
        }
      }
    }
  }
}

// ---------------- pool (batch sorted -> run-length accumulate) + fc ----------------
__global__ __launch_bounds__(256) void k_pool(const float* __restrict__ h, const int* __restrict__ batch,
                                              float* __restrict__ g, int n) {
  int c = threadIdx.x & 63;
  int rg = threadIdx.x >> 6;
  int start = blockIdx.x * POOL_NODES;
  float cur = 0.f;
  int curg = -1;
  for (int j = rg; j < POOL_NODES; j += 4) {
    int i = start + j;
    if (i >= n) break;
    int b = batch[i];
    if (b != curg) {
      if (curg >= 0) atomicAdd(&g[curg * CH + c], cur);
      curg = b;
      cur = 0.f;
    }
    cur += h[(size_t)i * CH + c];
  }
  if (curg >= 0) atomicAdd(&g[curg * CH + c], cur);
}

__global__ __launch_bounds__(256) void k_fc(const float* __restrict__ g, const float* __restrict__ Wfc,
                                            const float* __restrict__ bfc, float* __restrict__ outp,
                                            int ng, int oc) {
  int i = blockIdx.x * 256 + threadIdx.x;
  if (i < ng * oc) {
    int gi = i / oc, o = i - gi * oc;
    float s = bfc[o];
    for (int ci = 0; ci < CH; ++ci) s += g[gi * CH + ci] * Wfc[ci * oc + o];
    outp[i] = s;
  }
}

extern "C" void kernel_launch(void* const* d_in, const int* in_sizes, int n_in,
                              void* d_out, int out_size, void* d_ws, size_t ws_size,
                              hipStream_t stream) {
  const float* x   = (const float*)d_in[0];
  const int* eidx  = (const int*)d_in[1];
  const int* batch = (const int*)d_in[2];
  const float* W1  = (const float*)d_in[3];
  const float* b1  = (const float*)d_in[4];
  const float* W2  = (const float*)d_in[5];
  const float* b2  = (const float*)d_in[6];
  const float* Wfc = (const float*)d_in[7];
  const float* bfc = (const float*)d_in[8];
  float* out = (float*)d_out;

  const int n  = in_sizes[0] / CH;        // 100000
  const int E  = in_sizes[1] / 2;         // 1250000
  const int OC = in_sizes[8];             // 10
  const int NG = out_size / OC;           // 64

  const int* src = eidx;
  const int* dst = eidx + E;

  size_t off = 0;
  char* base = (char*)d_ws;
  auto alloc = [&](size_t bytes) -> void* {
    size_t cur = (off + 255) & ~(size_t)255;
    off = cur + bytes;
    return (void*)(base + cur);
  };
  int*   deg_src = (int*)alloc((size_t)n * 4);
  int*   cnt_dst = (int*)alloc((size_t)n * 4);
  float* neg_inv = (float*)alloc((size_t)n * 4);
  int*   row_ptr = (int*)alloc((size_t)(n + 1) * 4);
  int*   cursor  = (int*)alloc((size_t)n * 4);
  const int nb   = (n + 1023) / 1024;
  int*   bsum    = (int*)alloc((size_t)nb * 4);
  int2*  erec    = (int2*)alloc((size_t)E * 8);
  const size_t tbytes = (size_t)n * CH * 4;
  float* T1 = (float*)alloc(tbytes);
  float* T2 = (float*)alloc(tbytes);
  float* T3 = (float*)alloc(tbytes);
  float* T4 = (float*)alloc(tbytes);
  float* H  = (float*)alloc(tbytes);
  float* g  = (float*)alloc((size_t)NG * CH * 4);
  unsigned short* Wt1 = (unsigned short*)alloc(64 * 320 * 2);
  unsigned short* Wt2 = (unsigned short*)alloc(64 * 320 * 2);
  if (off > ws_size) return;  // workspace too small -> fail loudly (zeros out)

  hipMemsetAsync(deg_src, 0, (size_t)n * 4, stream);
  hipMemsetAsync(cnt_dst, 0, (size_t)n * 4, stream);
  hipMemsetAsync(g, 0, (size_t)NG * CH * 4, stream);

  const int eb  = (E + 255) / 256;
  const int nbk = (n + 255) / 256;
  k_hist<<<eb, 256, 0, stream>>>(src, dst, deg_src, cnt_dst, E);
  k_neg_inv<<<nbk, 256, 0, stream>>>(deg_src, neg_inv, n);
  k_scan_local<<<nb, 256, 0, stream>>>(cnt_dst, row_ptr, bsum, n);
  k_scan_bsums<<<1, 128, 0, stream>>>(bsum, nb);
  k_scan_add<<<(n + 1 + 255) / 256, 256, 0, stream>>>(row_ptr, bsum, cursor, n, E);
  k_scatter<<<eb, 256, 0, stream>>>(src, dst, neg_inv, cursor, erec, E);
  k_prepW<<<80, 256, 0, stream>>>(W1, Wt1);
  k_prepW<<<80, 256, 0, stream>>>(W2, Wt2);

  const int pb = (n + 3) / 4;
  const int gb = (n + 63) / 64;
  // layer 1: Tx rotation T1..T4, then fused bf16-MFMA matmul+bias+selu -> H
  k_prop<<<pb, 256, 0, stream>>>(row_ptr, erec, x,  nullptr, T1, n, 1);
  k_prop<<<pb, 256, 0, stream>>>(row_ptr, erec, T1, x,  T2, n, 2);
  k_prop<<<pb, 256, 0, stream>>>(row_ptr, erec, T2, T1, T3, n, 2);
  k_prop<<<pb, 256, 0, stream>>>(row_ptr, erec, T3, T2, T4, n, 2);
  k_gemm5<<<gb, 256, 0, stream>>>(x, T1, T2, T3, T4, Wt1, b1, H, n);
  // layer 2 (in-place H: each block stages its own 64 rows before writing them)
  k_prop<<<pb, 256, 0, stream>>>(row_ptr, erec, H,  nullptr, T1, n, 1);
  k_prop<<<pb, 256, 0, stream>>>(row_ptr, erec, T1, H,  T2, n, 2);
  k_prop<<<pb, 256, 0, stream>>>(row_ptr, erec, T2, T1, T3, n, 2);
  k_prop<<<pb, 256, 0, stream>>>(row_ptr, erec, T3, T2, T4, n, 2);
  k_gemm5<<<gb, 256, 0, stream>>>(H, T1, T2, T3, T4, Wt2, b2, H, n);
  // pool + fc
  k_pool<<<(n + POOL_NODES - 1) / POOL_NODES, 256, 0, stream>>>(H, batch, g, n);
  k_fc<<<(NG * OC + 255) / 256, 256, 0, stream>>>(g, Wfc, bfc, out, NG, OC);
}

// Round 3
// 769.118 us; speedup vs baseline: 1.9836x; 1.6820x over previous
//
#include <hip/hip_runtime.h>
#include <cstdint>

#define CH 64
#define POOL_NODES 256

typedef __attribute__((ext_vector_type(8))) short bf16x8;
typedef __attribute__((ext_vector_type(8))) unsigned short u16x8;
typedef __attribute__((ext_vector_type(4))) float f32x4;

__device__ __forceinline__ unsigned short f2bf(float x) {
  unsigned u = __float_as_uint(x);
  u += 0x7FFF + ((u >> 16) & 1);          // round-to-nearest-even
  return (unsigned short)(u >> 16);
}
__device__ __forceinline__ float bf2f(unsigned short h) {
  return __uint_as_float(((unsigned)h) << 16);
}

// ---------------- preprocessing: degree, CSR-by-dst ----------------
__global__ __launch_bounds__(256) void k_hist(const int* __restrict__ src, const int* __restrict__ dst,
                                              int* __restrict__ deg_src, int* __restrict__ cnt_dst, int E) {
  int e = blockIdx.x * 256 + threadIdx.x;
  if (e < E) {
    atomicAdd(&deg_src[src[e]], 1);
    atomicAdd(&cnt_dst[dst[e]], 1);
  }
}

__global__ __launch_bounds__(256) void k_neg_inv(const int* __restrict__ deg, float* __restrict__ neg_inv, int n) {
  int i = blockIdx.x * 256 + threadIdx.x;
  if (i < n) {
    int d = deg[i];
    neg_inv[i] = d > 0 ? (-1.0f / (float)d) : 0.0f;   // ew = -1/deg[src]
  }
}

// exclusive scan of cnt (1024 elems/block) -> row_ptr, block totals -> bsum
__global__ __launch_bounds__(256) void k_scan_local(const int* __restrict__ cnt, int* __restrict__ row_ptr,
                                                    int* __restrict__ bsum, int n) {
  __shared__ int s[256];
  int t = threadIdx.x;
  int base = blockIdx.x * 1024 + t * 4;
  int v0 = (base + 0 < n) ? cnt[base + 0] : 0;
  int v1 = (base + 1 < n) ? cnt[base + 1] : 0;
  int v2 = (base + 2 < n) ? cnt[base + 2] : 0;
  int v3 = (base + 3 < n) ? cnt[base + 3] : 0;
  int sum = v0 + v1 + v2 + v3;
  s[t] = sum;
  __syncthreads();
  for (int off = 1; off < 256; off <<= 1) {
    int x = (t >= off) ? s[t - off] : 0;
    __syncthreads();
    s[t] += x;
    __syncthreads();
  }
  int excl = s[t] - sum;
  if (base + 0 < n) row_ptr[base + 0] = excl;  excl += v0;
  if (base + 1 < n) row_ptr[base + 1] = excl;  excl += v1;
  if (base + 2 < n) row_ptr[base + 2] = excl;  excl += v2;
  if (base + 3 < n) row_ptr[base + 3] = excl;
  if (t == 255) bsum[blockIdx.x] = s[255];
}

// parallel exclusive scan of the (<=128) block sums
__global__ __launch_bounds__(128) void k_scan_bsums(int* bsum, int nb) {
  __shared__ int s[128];
  int t = threadIdx.x;
  int v = (t < nb) ? bsum[t] : 0;
  s[t] = v;
  __syncthreads();
  for (int off = 1; off < 128; off <<= 1) {
    int x = (t >= off) ? s[t - off] : 0;
    __syncthreads();
    s[t] += x;
    __syncthreads();
  }
  if (t < nb) bsum[t] = s[t] - v;   // exclusive
}

__global__ __launch_bounds__(256) void k_scan_add(int* __restrict__ row_ptr, const int* __restrict__ bsum,
                                                  int* __restrict__ cursor, int n, int E) {
  int i = blockIdx.x * 256 + threadIdx.x;
  if (i < n) {
    int v = row_ptr[i] + bsum[i >> 10];
    row_ptr[i] = v;
    cursor[i] = v;
  } else if (i == n) {
    row_ptr[n] = E;
  }
}

// pack (src, ew) per edge, sorted by dst via atomic cursors
__global__ __launch_bounds__(256) void k_scatter(const int* __restrict__ src, const int* __restrict__ dst,
                                                 const float* __restrict__ neg_inv, int* __restrict__ cursor,
                                                 int2* __restrict__ erec, int E) {
  int e = blockIdx.x * 256 + threadIdx.x;
  if (e < E) {
    int d = dst[e];
    int p = atomicAdd(&cursor[d], 1);
    int s = src[e];
    erec[p] = make_int2(s, __float_as_int(neg_inv[s]));
  }
}

// ---------------- fp32 -> bf16 cast ----------------
__global__ __launch_bounds__(256) void k_cast(const float* __restrict__ x, unsigned short* __restrict__ xb,
                                              int total8) {
  int i = blockIdx.x * 256 + threadIdx.x;
  if (i < total8) {
    const float4* p = (const float4*)(x + (size_t)i * 8);
    float4 v0 = p[0], v1 = p[1];
    u16x8 w;
    w[0] = f2bf(v0.x); w[1] = f2bf(v0.y); w[2] = f2bf(v0.z); w[3] = f2bf(v0.w);
    w[4] = f2bf(v1.x); w[5] = f2bf(v1.y); w[6] = f2bf(v1.z); w[7] = f2bf(v1.w);
    *(u16x8*)(xb + (size_t)i * 8) = w;
  }
}

// ---------------- sparse propagation: one wave per node, lane = channel, bf16 rows ----------------
// mode 1: t_out = prop(t_in);  mode 2: t_out = 2*prop(t_in) - t_sub
// 4-way unrolled edge loop: 4 independent accumulators -> 4 outstanding gathers.
__global__ __launch_bounds__(256) void k_prop(const int* __restrict__ row_ptr, const int2* __restrict__ erec,
                                              const unsigned short* __restrict__ t_in,
                                              const unsigned short* __restrict__ t_sub,
                                              unsigned short* __restrict__ t_out, int n, int mode) {
  int tid = threadIdx.x;
  int lane = tid & 63;
  int node = blockIdx.x * 4 + (tid >> 6);
  if (node >= n) return;
  int beg = row_ptr[node], end = row_ptr[node + 1];
  float s0 = 0.f, s1 = 0.f, s2 = 0.f, s3 = 0.f;
  int e = beg;
  for (; e + 4 <= end; e += 4) {
    int2 r0 = erec[e + 0];                 // uniform -> scalar loads
    int2 r1 = erec[e + 1];
    int2 r2 = erec[e + 2];
    int2 r3 = erec[e + 3];
    float v0 = bf2f(t_in[(size_t)r0.x * CH + lane]);   // 4 independent 128B gathers
    float v1 = bf2f(t_in[(size_t)r1.x * CH + lane]);
    float v2 = bf2f(t_in[(size_t)r2.x * CH + lane]);
    float v3 = bf2f(t_in[(size_t)r3.x * CH + lane]);
    s0 = fmaf(__int_as_float(r0.y), v0, s0);
    s1 = fmaf(__int_as_float(r1.y), v1, s1);
    s2 = fmaf(__int_as_float(r2.y), v2, s2);
    s3 = fmaf(__int_as_float(r3.y), v3, s3);
  }
  for (; e < end; ++e) {
    int2 r = erec[e];
    s0 = fmaf(__int_as_float(r.y), bf2f(t_in[(size_t)r.x * CH + lane]), s0);
  }
  float s = (s0 + s1) + (s2 + s3);
  float val = (mode == 1) ? s : (2.0f * s - bf2f(t_sub[(size_t)node * CH + lane]));
  t_out[(size_t)node * CH + lane] = f2bf(val);
}

// ---------------- W transpose + bf16 convert: Wt[j*320 + k] = bf16(W[k*64 + j]) ----------------
__global__ __launch_bounds__(256) void k_prepW(const float* __restrict__ W, unsigned short* __restrict__ Wt) {
  int o = blockIdx.x * 256 + threadIdx.x;  // o = j*320 + k
  if (o < 64 * 320) {
    int j = o / 320, k = o - j * 320;
    Wt[o] = f2bf(W[k * 64 + j]);
  }
}

// ---------------- fused out = selu([M0|..|M4] @ stackedW + b), bf16 MFMA ----------------
// A matrices are bf16 in global; staged into 40KB swizzled LDS (no convert).
// OutT selects fp32 (layer 2, feeds pool) or bf16 (layer 1, feeds props/gemm).
template <typename OutT>
__global__ __launch_bounds__(256) void k_gemm5(
    const unsigned short* __restrict__ M0, const unsigned short* __restrict__ M1,
    const unsigned short* __restrict__ M2, const unsigned short* __restrict__ M3,
    const unsigned short* __restrict__ M4,
    const unsigned short* __restrict__ Wt, const float* __restrict__ bias,
    OutT* __restrict__ outp, int n) {
  __shared__ unsigned short lds[64 * 320];  // 40KB, A tile, 16B-chunk XOR swizzle
  const int t = threadIdx.x;
  const int lane = t & 63, wave = t >> 6;
  const int node0 = blockIdx.x * 64;
  const unsigned short* mats[5] = {M0, M1, M2, M3, M4};
  // ---- stage A: per mat 64 rows x 8 chunks(16B) = 512 chunks, 2 per thread ----
#pragma unroll
  for (int m = 0; m < 5; ++m) {
    const unsigned short* __restrict__ T = mats[m];
#pragma unroll
    for (int i = 0; i < 2; ++i) {
      int flat = i * 256 + t;               // 0..511
      int row = flat >> 3;                  // 0..63
      int cc = flat & 7;                    // 16B chunk within this mat's row
      int ca = m * 8 + cc;                  // chunk index within 320-col row
      u16x8 w = {};
      if (node0 + row < n)
        w = *(const u16x8*)(T + (size_t)(node0 + row) * CH + cc * 8);
      *(u16x8*)(&lds[row * 320 + ((ca ^ (row & 7)) << 3)]) = w;
    }
  }
  __syncthreads();
  // ---- MFMA: wave (wr,wc) computes rows wr*32..+31, cols wc*32..+31 ----
  const int wr = wave >> 1, wc = wave & 1;
  const int g = lane >> 4, r16 = lane & 15;
  const int rowA0 = wr * 32 + r16, rowA1 = rowA0 + 16;
  const int colB0 = wc * 32 + r16, colB1 = colB0 + 16;
  f32x4 acc00 = {}, acc01 = {}, acc10 = {}, acc11 = {};
#pragma unroll 2
  for (int kk = 0; kk < 10; ++kk) {
    int ca = kk * 4 + g;
    bf16x8 a0 = *(const bf16x8*)(&lds[rowA0 * 320 + ((ca ^ (rowA0 & 7)) << 3)]);
    bf16x8 a1 = *(const bf16x8*)(&lds[rowA1 * 320 + ((ca ^ (rowA1 & 7)) << 3)]);
    bf16x8 b0 = *(const bf16x8*)(Wt + colB0 * 320 + kk * 32 + g * 8);
    bf16x8 b1 = *(const bf16x8*)(Wt + colB1 * 320 + kk * 32 + g * 8);
    acc00 = __builtin_amdgcn_mfma_f32_16x16x32_bf16(a0, b0, acc00, 0, 0, 0);
    acc01 = __builtin_amdgcn_mfma_f32_16x16x32_bf16(a0, b1, acc01, 0, 0, 0);
    acc10 = __builtin_amdgcn_mfma_f32_16x16x32_bf16(a1, b0, acc10, 0, 0, 0);
    acc11 = __builtin_amdgcn_mfma_f32_16x16x32_bf16(a1, b1, acc11, 0, 0, 0);
  }
  // ---- epilogue: bias + selu + store (C/D: col=lane&15, row=4*(lane>>4)+reg) ----
  const float sc = 1.0507009873554805f, al = 1.6732632423543773f;
  const f32x4 accs[2][2] = {{acc00, acc01}, {acc10, acc11}};
#pragma unroll
  for (int i = 0; i < 2; ++i) {
#pragma unroll
    for (int j = 0; j < 2; ++j) {
      int col = wc * 32 + j * 16 + r16;
      float bv = bias[col];
#pragma unroll
      for (int rr = 0; rr < 4; ++rr) {
        int row = node0 + wr * 32 + i * 16 + g * 4 + rr;
        if (row < n) {
          float v = accs[i][j][rr] + bv;
          v = (v > 0.f) ? (sc * v) : (sc * al * (expf(v) - 1.f));
          if constexpr (sizeof(OutT) == 4) outp[(size_t)row * CH + col] = (OutT)v;
          else outp[(size_t)row * CH + col] = (OutT)f2bf(v);
        }
      }
    }
  }
}

// ---------------- pool (batch sorted -> run-length accumulate) + fc ----------------
__global__ __launch_bounds__(256) void k_pool(const float* __restrict__ h, const int* __restrict__ batch,
                                              float* __restrict__ g, int n) {
  int c = threadIdx.x & 63;
  int rg = threadIdx.x >> 6;
  int start = blockIdx.x * POOL_NODES;
  float cur = 0.f;
  int curg = -1;
  for (int j = rg; j < POOL_NODES; j += 4) {
    int i = start + j;
    if (i >= n) break;
    int b = batch[i];
    if (b != curg) {
      if (curg >= 0) atomicAdd(&g[curg * CH + c], cur);
      curg = b;
      cur = 0.f;
    }
    cur += h[(size_t)i * CH + c];
  }
  if (curg >= 0) atomicAdd(&g[curg * CH + c], cur);
}

__global__ __launch_bounds__(256) void k_fc(const float* __restrict__ g, const float* __restrict__ Wfc,
                                            const float* __restrict__ bfc, float* __restrict__ outp,
                                            int ng, int oc) {
  int i = blockIdx.x * 256 + threadIdx.x;
  if (i < ng * oc) {
    int gi = i / oc, o = i - gi * oc;
    float s = bfc[o];
    for (int ci = 0; ci < CH; ++ci) s += g[gi * CH + ci] * Wfc[ci * oc + o];
    outp[i] = s;
  }
}

extern "C" void kernel_launch(void* const* d_in, const int* in_sizes, int n_in,
                              void* d_out, int out_size, void* d_ws, size_t ws_size,
                              hipStream_t stream) {
  const float* x   = (const float*)d_in[0];
  const int* eidx  = (const int*)d_in[1];
  const int* batch = (const int*)d_in[2];
  const float* W1  = (const float*)d_in[3];
  const float* b1  = (const float*)d_in[4];
  const float* W2  = (const float*)d_in[5];
  const float* b2  = (const float*)d_in[6];
  const float* Wfc = (const float*)d_in[7];
  const float* bfc = (const float*)d_in[8];
  float* out = (float*)d_out;

  const int n  = in_sizes[0] / CH;        // 100000
  const int E  = in_sizes[1] / 2;         // 1250000
  const int OC = in_sizes[8];             // 10
  const int NG = out_size / OC;           // 64

  const int* src = eidx;
  const int* dst = eidx + E;

  size_t off = 0;
  char* base = (char*)d_ws;
  auto alloc = [&](size_t bytes) -> void* {
    size_t cur = (off + 255) & ~(size_t)255;
    off = cur + bytes;
    return (void*)(base + cur);
  };
  int*   deg_src = (int*)alloc((size_t)n * 4);
  int*   cnt_dst = (int*)alloc((size_t)n * 4);
  float* neg_inv = (float*)alloc((size_t)n * 4);
  int*   row_ptr = (int*)alloc((size_t)(n + 1) * 4);
  int*   cursor  = (int*)alloc((size_t)n * 4);
  const int nb   = (n + 1023) / 1024;
  int*   bsum    = (int*)alloc((size_t)nb * 4);
  int2*  erec    = (int2*)alloc((size_t)E * 8);
  const size_t tb16 = (size_t)n * CH * 2;
  unsigned short* Xb = (unsigned short*)alloc(tb16);
  unsigned short* T1 = (unsigned short*)alloc(tb16);
  unsigned short* T2 = (unsigned short*)alloc(tb16);
  unsigned short* T3 = (unsigned short*)alloc(tb16);
  unsigned short* T4 = (unsigned short*)alloc(tb16);
  unsigned short* H  = (unsigned short*)alloc(tb16);
  float* H2 = (float*)alloc((size_t)n * CH * 4);
  float* g  = (float*)alloc((size_t)NG * CH * 4);
  unsigned short* Wt1 = (unsigned short*)alloc(64 * 320 * 2);
  unsigned short* Wt2 = (unsigned short*)alloc(64 * 320 * 2);
  if (off > ws_size) return;  // workspace too small -> fail loudly (zeros out)

  hipMemsetAsync(deg_src, 0, (size_t)n * 4, stream);
  hipMemsetAsync(cnt_dst, 0, (size_t)n * 4, stream);
  hipMemsetAsync(g, 0, (size_t)NG * CH * 4, stream);

  const int eb  = (E + 255) / 256;
  const int nbk = (n + 255) / 256;
  k_hist<<<eb, 256, 0, stream>>>(src, dst, deg_src, cnt_dst, E);
  k_neg_inv<<<nbk, 256, 0, stream>>>(deg_src, neg_inv, n);
  k_scan_local<<<nb, 256, 0, stream>>>(cnt_dst, row_ptr, bsum, n);
  k_scan_bsums<<<1, 128, 0, stream>>>(bsum, nb);
  k_scan_add<<<(n + 1 + 255) / 256, 256, 0, stream>>>(row_ptr, bsum, cursor, n, E);
  k_scatter<<<eb, 256, 0, stream>>>(src, dst, neg_inv, cursor, erec, E);
  k_prepW<<<80, 256, 0, stream>>>(W1, Wt1);
  k_prepW<<<80, 256, 0, stream>>>(W2, Wt2);
  k_cast<<<(n * CH / 8 + 255) / 256, 256, 0, stream>>>(x, Xb, n * CH / 8);

  const int pb = (n + 3) / 4;
  const int gb = (n + 63) / 64;
  // layer 1: Tx rotation T1..T4 (bf16), then fused bf16-MFMA matmul+bias+selu -> H (bf16)
  k_prop<<<pb, 256, 0, stream>>>(row_ptr, erec, Xb, nullptr, T1, n, 1);
  k_prop<<<pb, 256, 0, stream>>>(row_ptr, erec, T1, Xb, T2, n, 2);
  k_prop<<<pb, 256, 0, stream>>>(row_ptr, erec, T2, T1, T3, n, 2);
  k_prop<<<pb, 256, 0, stream>>>(row_ptr, erec, T3, T2, T4, n, 2);
  k_gemm5<unsigned short><<<gb, 256, 0, stream>>>(Xb, T1, T2, T3, T4, Wt1, b1, H, n);
  // layer 2 -> H2 (fp32, feeds pool)
  k_prop<<<pb, 256, 0, stream>>>(row_ptr, erec, H,  nullptr, T1, n, 1);
  k_prop<<<pb, 256, 0, stream>>>(row_ptr, erec, T1, H,  T2, n, 2);
  k_prop<<<pb, 256, 0, stream>>>(row_ptr, erec, T2, T1, T3, n, 2);
  k_prop<<<pb, 256, 0, stream>>>(row_ptr, erec, T3, T2, T4, n, 2);
  k_gemm5<float><<<gb, 256, 0, stream>>>(H, T1, T2, T3, T4, Wt2, b2, H2, n);
  // pool + fc
  k_pool<<<(n + POOL_NODES - 1) / POOL_NODES, 256, 0, stream>>>(H2, batch, g, n);
  k_fc<<<(NG * OC + 255) / 256, 256, 0, stream>>>(g, Wfc, bfc, out, NG, OC);
}

// Round 4
// 606.009 us; speedup vs baseline: 2.5175x; 1.2692x over previous
//
#include <hip/hip_runtime.h>
#include <cstdint>

#define CH 64
#define POOL_NODES 256
#define NBLK 256          // blocks in bucket passes
#define NBMAX 1024        // max coarse buckets (n <= 131072)

typedef __attribute__((ext_vector_type(8))) short bf16x8;
typedef __attribute__((ext_vector_type(8))) unsigned short u16x8;
typedef __attribute__((ext_vector_type(4))) float f32x4;

__device__ __forceinline__ unsigned short f2bf(float x) {
  unsigned u = __float_as_uint(x);
  u += 0x7FFF + ((u >> 16) & 1);          // round-to-nearest-even
  return (unsigned short)(u >> 16);
}
__device__ __forceinline__ float bf2f(unsigned short h) {
  return __uint_as_float(((unsigned)h) << 16);
}

// ---------------- phase 1: per-block LDS histograms of dst>>7 and src>>7 ----------------
__global__ __launch_bounds__(256) void k_b1(const int* __restrict__ src, const int* __restrict__ dst,
                                            int* __restrict__ cntD, int* __restrict__ cntS, int E, int NB) {
  __shared__ int hD[NBMAX], hS[NBMAX];
  int t = threadIdx.x, b = blockIdx.x;
  for (int i = t; i < NBMAX; i += 256) { hD[i] = 0; hS[i] = 0; }
  __syncthreads();
  int chunk = (E + NBLK - 1) / NBLK;
  int e0 = b * chunk, e1 = min(E, e0 + chunk);
  for (int e = e0 + t; e < e1; e += 256) {
    atomicAdd(&hD[dst[e] >> 7], 1);
    atomicAdd(&hS[src[e] >> 7], 1);
  }
  __syncthreads();
  for (int i = t; i < NB; i += 256) {
    cntD[i * NBLK + b] = hD[i];
    cntS[i * NBLK + b] = hS[i];
  }
}

// ---------------- generic 2-level exclusive scan (in-place capable) ----------------
__global__ __launch_bounds__(256) void k_scan_local(const int* __restrict__ in, int* __restrict__ out,
                                                    int* __restrict__ bsum, int total) {
  __shared__ int s[256];
  int t = threadIdx.x;
  int base = blockIdx.x * 1024 + t * 4;
  int v0 = (base + 0 < total) ? in[base + 0] : 0;
  int v1 = (base + 1 < total) ? in[base + 1] : 0;
  int v2 = (base + 2 < total) ? in[base + 2] : 0;
  int v3 = (base + 3 < total) ? in[base + 3] : 0;
  int sum = v0 + v1 + v2 + v3;
  s[t] = sum;
  __syncthreads();
  for (int off = 1; off < 256; off <<= 1) {
    int x = (t >= off) ? s[t - off] : 0;
    __syncthreads();
    s[t] += x;
    __syncthreads();
  }
  int excl = s[t] - sum;
  if (base + 0 < total) out[base + 0] = excl;  excl += v0;
  if (base + 1 < total) out[base + 1] = excl;  excl += v1;
  if (base + 2 < total) out[base + 2] = excl;  excl += v2;
  if (base + 3 < total) out[base + 3] = excl;
  if (t == 255) bsum[blockIdx.x] = s[255];
}

__global__ __launch_bounds__(256) void k_scan_bsums(int* bsum, int nb) {
  __shared__ int s[256];
  int t = threadIdx.x;
  int v = (t < nb) ? bsum[t] : 0;
  s[t] = v;
  __syncthreads();
  for (int off = 1; off < 256; off <<= 1) {
    int x = (t >= off) ? s[t - off] : 0;
    __syncthreads();
    s[t] += x;
    __syncthreads();
  }
  if (t < nb) bsum[t] = s[t] - v;   // exclusive
}

__global__ __launch_bounds__(256) void k_scan_add(int* __restrict__ arr, const int* __restrict__ bsum, int total) {
  int i = blockIdx.x * 256 + threadIdx.x;
  if (i < total) arr[i] += bsum[i >> 10];
}

// ---------------- phase 2: atomic-free scatter into bucket-grouped order ----------------
__global__ __launch_bounds__(256) void k_b2(const int* __restrict__ src, const int* __restrict__ dst,
                                            const int* __restrict__ cbaseD, const int* __restrict__ cbaseS,
                                            int2* __restrict__ erec_tmp, int* __restrict__ svals, int E, int NB) {
  __shared__ int curD[NBMAX], curS[NBMAX];
  int t = threadIdx.x, b = blockIdx.x;
  for (int i = t; i < NB; i += 256) {
    curD[i] = cbaseD[i * NBLK + b];
    curS[i] = cbaseS[i * NBLK + b];
  }
  __syncthreads();
  int chunk = (E + NBLK - 1) / NBLK;
  int e0 = b * chunk, e1 = min(E, e0 + chunk);
  for (int e = e0 + t; e < e1; e += 256) {
    int s = src[e], d = dst[e];
    int pd = atomicAdd(&curD[d >> 7], 1);
    erec_tmp[pd] = make_int2(s, d);
    int ps = atomicAdd(&curS[s >> 7], 1);
    svals[ps] = s;
  }
}

// ---------------- phase 3a: exact out-degree per node -> neg_inv ----------------
__global__ __launch_bounds__(256) void k_b3_deg(const int* __restrict__ svals, const int* __restrict__ cbaseS,
                                                float* __restrict__ neg_inv, int n, int E, int NB) {
  __shared__ int h[128];
  int t = threadIdx.x, k = blockIdx.x;
  if (t < 128) h[t] = 0;
  __syncthreads();
  int lo = cbaseS[k * NBLK];
  int hi = (k + 1 < NB) ? cbaseS[(k + 1) * NBLK] : E;
  for (int e = lo + t; e < hi; e += 256) atomicAdd(&h[svals[e] & 127], 1);
  __syncthreads();
  if (t < 128) {
    int node = k * 128 + t;
    if (node < n) {
      int c = h[t];
      neg_inv[node] = c > 0 ? (-1.0f / (float)c) : 0.0f;
    }
  }
}

// ---------------- phase 3b: per-bucket exact counting sort -> erec + row_ptr ----------------
__global__ __launch_bounds__(256) void k_b3_dst(const int2* __restrict__ erec_tmp, const int* __restrict__ cbaseD,
                                                const float* __restrict__ neg_inv, int2* __restrict__ erec,
                                                int* __restrict__ row_ptr, int n, int E, int NB) {
  __shared__ int h[128], sc[128], cur[128];
  int t = threadIdx.x, k = blockIdx.x;
  if (t < 128) h[t] = 0;
  __syncthreads();
  int lo = cbaseD[k * NBLK];
  int hi = (k + 1 < NB) ? cbaseD[(k + 1) * NBLK] : E;
  for (int e = lo + t; e < hi; e += 256) atomicAdd(&h[erec_tmp[e].y & 127], 1);
  __syncthreads();
  if (t < 128) sc[t] = h[t];
  __syncthreads();
  for (int off = 1; off < 128; off <<= 1) {
    int x = (t < 128 && t >= off) ? sc[t - off] : 0;
    __syncthreads();
    if (t < 128) sc[t] += x;
    __syncthreads();
  }
  if (t < 128) {
    int excl = sc[t] - h[t];
    cur[t] = excl;
    int node = k * 128 + t;
    if (node < n) row_ptr[node] = lo + excl;
  }
  if (k == NB - 1 && t == 0) row_ptr[n] = E;
  __syncthreads();
  for (int e = lo + t; e < hi; e += 256) {
    int2 r = erec_tmp[e];
    int pos = atomicAdd(&cur[r.y & 127], 1);
    erec[lo + pos] = make_int2(r.x, __float_as_int(neg_inv[r.x]));
  }
}

// ---------------- fp32 -> bf16 cast ----------------
__global__ __launch_bounds__(256) void k_cast(const float* __restrict__ x, unsigned short* __restrict__ xb,
                                              int total8) {
  int i = blockIdx.x * 256 + threadIdx.x;
  if (i < total8) {
    const float4* p = (const float4*)(x + (size_t)i * 8);
    float4 v0 = p[0], v1 = p[1];
    u16x8 w;
    w[0] = f2bf(v0.x); w[1] = f2bf(v0.y); w[2] = f2bf(v0.z); w[3] = f2bf(v0.w);
    w[4] = f2bf(v1.x); w[5] = f2bf(v1.y); w[6] = f2bf(v1.z); w[7] = f2bf(v1.w);
    *(u16x8*)(xb + (size_t)i * 8) = w;
  }
}

// ---------------- sparse propagation: one wave per node, lane = channel, bf16 rows ----------------
// mode 1: t_out = prop(t_in);  mode 2: t_out = 2*prop(t_in) - t_sub
// 8-deep unrolled edge loop -> 8 outstanding gathers; 4-wide + scalar tail.
__global__ __launch_bounds__(256) void k_prop(const int* __restrict__ row_ptr, const int2* __restrict__ erec,
                                              const unsigned short* __restrict__ t_in,
                                              const unsigned short* __restrict__ t_sub,
                                              unsigned short* __restrict__ t_out, int n, int mode) {
  int tid = threadIdx.x;
  int lane = tid & 63;
  int node = blockIdx.x * 4 + (tid >> 6);
  if (node >= n) return;
  int beg = row_ptr[node], end = row_ptr[node + 1];
  float s0 = 0.f, s1 = 0.f, s2 = 0.f, s3 = 0.f, s4 = 0.f, s5 = 0.f, s6 = 0.f, s7 = 0.f;
  int e = beg;
  for (; e + 8 <= end; e += 8) {
    int2 r0 = erec[e + 0]; int2 r1 = erec[e + 1]; int2 r2 = erec[e + 2]; int2 r3 = erec[e + 3];
    int2 r4 = erec[e + 4]; int2 r5 = erec[e + 5]; int2 r6 = erec[e + 6]; int2 r7 = erec[e + 7];
    float v0 = bf2f(t_in[(size_t)r0.x * CH + lane]);
    float v1 = bf2f(t_in[(size_t)r1.x * CH + lane]);
    float v2 = bf2f(t_in[(size_t)r2.x * CH + lane]);
    float v3 = bf2f(t_in[(size_t)r3.x * CH + lane]);
    float v4 = bf2f(t_in[(size_t)r4.x * CH + lane]);
    float v5 = bf2f(t_in[(size_t)r5.x * CH + lane]);
    float v6 = bf2f(t_in[(size_t)r6.x * CH + lane]);
    float v7 = bf2f(t_in[(size_t)r7.x * CH + lane]);
    s0 = fmaf(__int_as_float(r0.y), v0, s0);
    s1 = fmaf(__int_as_float(r1.y), v1, s1);
    s2 = fmaf(__int_as_float(r2.y), v2, s2);
    s3 = fmaf(__int_as_float(r3.y), v3, s3);
    s4 = fmaf(__int_as_float(r4.y), v4, s4);
    s5 = fmaf(__int_as_float(r5.y), v5, s5);
    s6 = fmaf(__int_as_float(r6.y), v6, s6);
    s7 = fmaf(__int_as_float(r7.y), v7, s7);
  }
  if (e + 4 <= end) {
    int2 r0 = erec[e + 0]; int2 r1 = erec[e + 1]; int2 r2 = erec[e + 2]; int2 r3 = erec[e + 3];
    float v0 = bf2f(t_in[(size_t)r0.x * CH + lane]);
    float v1 = bf2f(t_in[(size_t)r1.x * CH + lane]);
    float v2 = bf2f(t_in[(size_t)r2.x * CH + lane]);
    float v3 = bf2f(t_in[(size_t)r3.x * CH + lane]);
    s0 = fmaf(__int_as_float(r0.y), v0, s0);
    s1 = fmaf(__int_as_float(r1.y), v1, s1);
    s2 = fmaf(__int_as_float(r2.y), v2, s2);
    s3 = fmaf(__int_as_float(r3.y), v3, s3);
    e += 4;
  }
  for (; e < end; ++e) {
    int2 r = erec[e];
    s0 = fmaf(__int_as_float(r.y), bf2f(t_in[(size_t)r.x * CH + lane]), s0);
  }
  float s = ((s0 + s1) + (s2 + s3)) + ((s4 + s5) + (s6 + s7));
  float val = (mode == 1) ? s : (2.0f * s - bf2f(t_sub[(size_t)node * CH + lane]));
  t_out[(size_t)node * CH + lane] = f2bf(val);
}

// ---------------- W transpose + bf16 convert: Wt[j*320 + k] = bf16(W[k*64 + j]) ----------------
__global__ __launch_bounds__(256) void k_prepW(const float* __restrict__ W, unsigned short* __restrict__ Wt) {
  int o = blockIdx.x * 256 + threadIdx.x;  // o = j*320 + k
  if (o < 64 * 320) {
    int j = o / 320, k = o - j * 320;
    Wt[o] = f2bf(W[k * 64 + j]);
  }
}

// ---------------- fused out = selu([M0|..|M4] @ stackedW + b), bf16 MFMA ----------------
template <typename OutT>
__global__ __launch_bounds__(256) void k_gemm5(
    const unsigned short* __restrict__ M0, const unsigned short* __restrict__ M1,
    const unsigned short* __restrict__ M2, const unsigned short* __restrict__ M3,
    const unsigned short* __restrict__ M4,
    const unsigned short* __restrict__ Wt, const float* __restrict__ bias,
    OutT* __restrict__ outp, int n) {
  __shared__ unsigned short lds[64 * 320];  // 40KB, A tile, 16B-chunk XOR swizzle
  const int t = threadIdx.x;
  const int lane = t & 63, wave = t >> 6;
  const int node0 = blockIdx.x * 64;
  const unsigned short* mats[5] = {M0, M1, M2, M3, M4};
#pragma unroll
  for (int m = 0; m < 5; ++m) {
    const unsigned short* __restrict__ T = mats[m];
#pragma unroll
    for (int i = 0; i < 2; ++i) {
      int flat = i * 256 + t;               // 0..511
      int row = flat >> 3;                  // 0..63
      int cc = flat & 7;                    // 16B chunk within this mat's row
      int ca = m * 8 + cc;                  // chunk index within 320-col row
      u16x8 w = {};
      if (node0 + row < n)
        w = *(const u16x8*)(T + (size_t)(node0 + row) * CH + cc * 8);
      *(u16x8*)(&lds[row * 320 + ((ca ^ (row & 7)) << 3)]) = w;
    }
  }
  __syncthreads();
  const int wr = wave >> 1, wc = wave & 1;
  const int g = lane >> 4, r16 = lane & 15;
  const int rowA0 = wr * 32 + r16, rowA1 = rowA0 + 16;
  const int colB0 = wc * 32 + r16, colB1 = colB0 + 16;
  f32x4 acc00 = {}, acc01 = {}, acc10 = {}, acc11 = {};
#pragma unroll 2
  for (int kk = 0; kk < 10; ++kk) {
    int ca = kk * 4 + g;
    bf16x8 a0 = *(const bf16x8*)(&lds[rowA0 * 320 + ((ca ^ (rowA0 & 7)) << 3)]);
    bf16x8 a1 = *(const bf16x8*)(&lds[rowA1 * 320 + ((ca ^ (rowA1 & 7)) << 3)]);
    bf16x8 b0 = *(const bf16x8*)(Wt + colB0 * 320 + kk * 32 + g * 8);
    bf16x8 b1 = *(const bf16x8*)(Wt + colB1 * 320 + kk * 32 + g * 8);
    acc00 = __builtin_amdgcn_mfma_f32_16x16x32_bf16(a0, b0, acc00, 0, 0, 0);
    acc01 = __builtin_amdgcn_mfma_f32_16x16x32_bf16(a0, b1, acc01, 0, 0, 0);
    acc10 = __builtin_amdgcn_mfma_f32_16x16x32_bf16(a1, b0, acc10, 0, 0, 0);
    acc11 = __builtin_amdgcn_mfma_f32_16x16x32_bf16(a1, b1, acc11, 0, 0, 0);
  }
  const float sc = 1.0507009873554805f, al = 1.6732632423543773f;
  const f32x4 accs[2][2] = {{acc00, acc01}, {acc10, acc11}};
#pragma unroll
  for (int i = 0; i < 2; ++i) {
#pragma unroll
    for (int j = 0; j < 2; ++j) {
      int col = wc * 32 + j * 16 + r16;
      float bv = bias[col];
#pragma unroll
      for (int rr = 0; rr < 4; ++rr) {
        int row = node0 + wr * 32 + i * 16 + g * 4 + rr;
        if (row < n) {
          float v = accs[i][j][rr] + bv;
          v = (v > 0.f) ? (sc * v) : (sc * al * (expf(v) - 1.f));
          if constexpr (sizeof(OutT) == 4) outp[(size_t)row * CH + col] = (OutT)v;
          else outp[(size_t)row * CH + col] = (OutT)f2bf(v);
        }
      }
    }
  }
}

// ---------------- pool (batch sorted -> run-length accumulate) + fc ----------------
__global__ __launch_bounds__(256) void k_pool(const float* __restrict__ h, const int* __restrict__ batch,
                                              float* __restrict__ g, int n) {
  int c = threadIdx.x & 63;
  int rg = threadIdx.x >> 6;
  int start = blockIdx.x * POOL_NODES;
  float cur = 0.f;
  int curg = -1;
  for (int j = rg; j < POOL_NODES; j += 4) {
    int i = start + j;
    if (i >= n) break;
    int b = batch[i];
    if (b != curg) {
      if (curg >= 0) atomicAdd(&g[curg * CH + c], cur);
      curg = b;
      cur = 0.f;
    }
    cur += h[(size_t)i * CH + c];
  }
  if (curg >= 0) atomicAdd(&g[curg * CH + c], cur);
}

__global__ __launch_bounds__(256) void k_fc(const float* __restrict__ g, const float* __restrict__ Wfc,
                                            const float* __restrict__ bfc, float* __restrict__ outp,
                                            int ng, int oc) {
  int i = blockIdx.x * 256 + threadIdx.x;
  if (i < ng * oc) {
    int gi = i / oc, o = i - gi * oc;
    float s = bfc[o];
    for (int ci = 0; ci < CH; ++ci) s += g[gi * CH + ci] * Wfc[ci * oc + o];
    outp[i] = s;
  }
}

extern "C" void kernel_launch(void* const* d_in, const int* in_sizes, int n_in,
                              void* d_out, int out_size, void* d_ws, size_t ws_size,
                              hipStream_t stream) {
  const float* x   = (const float*)d_in[0];
  const int* eidx  = (const int*)d_in[1];
  const int* batch = (const int*)d_in[2];
  const float* W1  = (const float*)d_in[3];
  const float* b1  = (const float*)d_in[4];
  const float* W2  = (const float*)d_in[5];
  const float* b2  = (const float*)d_in[6];
  const float* Wfc = (const float*)d_in[7];
  const float* bfc = (const float*)d_in[8];
  float* out = (float*)d_out;

  const int n  = in_sizes[0] / CH;        // 100000
  const int E  = in_sizes[1] / 2;         // 1250000
  const int OC = in_sizes[8];             // 10
  const int NG = out_size / OC;           // 64
  const int NB = (n + 127) >> 7;          // 782 coarse buckets

  const int* src = eidx;
  const int* dst = eidx + E;

  size_t off = 0;
  char* base = (char*)d_ws;
  auto alloc = [&](size_t bytes) -> void* {
    size_t cur = (off + 255) & ~(size_t)255;
    off = cur + bytes;
    return (void*)(base + cur);
  };
  const int scan_total = NB * NBLK;                  // 200192
  const int scan_nb    = (scan_total + 1023) / 1024; // 196
  int*   cntD   = (int*)alloc((size_t)scan_total * 4);
  int*   cntS   = (int*)alloc((size_t)scan_total * 4);
  int*   bsumD  = (int*)alloc((size_t)scan_nb * 4);
  int*   bsumS  = (int*)alloc((size_t)scan_nb * 4);
  float* neg_inv = (float*)alloc((size_t)n * 4);
  int*   row_ptr = (int*)alloc((size_t)(n + 1) * 4);
  int2*  erec    = (int2*)alloc((size_t)E * 8);
  const size_t tb16 = (size_t)n * CH * 2;
  unsigned short* Xb = (unsigned short*)alloc(tb16);
  unsigned short* T1 = (unsigned short*)alloc(tb16);
  unsigned short* T2 = (unsigned short*)alloc(tb16);
  unsigned short* T3 = (unsigned short*)alloc(tb16);
  unsigned short* T4 = (unsigned short*)alloc(tb16);
  unsigned short* H  = (unsigned short*)alloc(tb16);
  float* H2 = (float*)alloc((size_t)n * CH * 4);
  float* g  = (float*)alloc((size_t)NG * CH * 4);
  unsigned short* Wt1 = (unsigned short*)alloc(64 * 320 * 2);
  unsigned short* Wt2 = (unsigned short*)alloc(64 * 320 * 2);
  if (off > ws_size) return;  // workspace too small -> fail loudly (zeros out)

  // preprocessing scratch aliases H2 (finished before H2 is written)
  int2* erec_tmp = (int2*)H2;
  int*  svals    = (int*)(erec_tmp + E);

  hipMemsetAsync(g, 0, (size_t)NG * CH * 4, stream);

  // ---- atomic-free CSR build ----
  k_b1<<<NBLK, 256, 0, stream>>>(src, dst, cntD, cntS, E, NB);
  k_scan_local<<<scan_nb, 256, 0, stream>>>(cntD, cntD, bsumD, scan_total);
  k_scan_bsums<<<1, 256, 0, stream>>>(bsumD, scan_nb);
  k_scan_add<<<(scan_total + 255) / 256, 256, 0, stream>>>(cntD, bsumD, scan_total);
  k_scan_local<<<scan_nb, 256, 0, stream>>>(cntS, cntS, bsumS, scan_total);
  k_scan_bsums<<<1, 256, 0, stream>>>(bsumS, scan_nb);
  k_scan_add<<<(scan_total + 255) / 256, 256, 0, stream>>>(cntS, bsumS, scan_total);
  k_b2<<<NBLK, 256, 0, stream>>>(src, dst, cntD, cntS, erec_tmp, svals, E, NB);
  k_b3_deg<<<NB, 256, 0, stream>>>(svals, cntS, neg_inv, n, E, NB);
  k_b3_dst<<<NB, 256, 0, stream>>>(erec_tmp, cntD, neg_inv, erec, row_ptr, n, E, NB);

  k_prepW<<<80, 256, 0, stream>>>(W1, Wt1);
  k_prepW<<<80, 256, 0, stream>>>(W2, Wt2);
  k_cast<<<(n * CH / 8 + 255) / 256, 256, 0, stream>>>(x, Xb, n * CH / 8);

  const int pb = (n + 3) / 4;
  const int gb = (n + 63) / 64;
  // layer 1
  k_prop<<<pb, 256, 0, stream>>>(row_ptr, erec, Xb, nullptr, T1, n, 1);
  k_prop<<<pb, 256, 0, stream>>>(row_ptr, erec, T1, Xb, T2, n, 2);
  k_prop<<<pb, 256, 0, stream>>>(row_ptr, erec, T2, T1, T3, n, 2);
  k_prop<<<pb, 256, 0, stream>>>(row_ptr, erec, T3, T2, T4, n, 2);
  k_gemm5<unsigned short><<<gb, 256, 0, stream>>>(Xb, T1, T2, T3, T4, Wt1, b1, H, n);
  // layer 2 -> H2 (fp32, feeds pool)
  k_prop<<<pb, 256, 0, stream>>>(row_ptr, erec, H,  nullptr, T1, n, 1);
  k_prop<<<pb, 256, 0, stream>>>(row_ptr, erec, T1, H,  T2, n, 2);
  k_prop<<<pb, 256, 0, stream>>>(row_ptr, erec, T2, T1, T3, n, 2);
  k_prop<<<pb, 256, 0, stream>>>(row_ptr, erec, T3, T2, T4, n, 2);
  k_gemm5<float><<<gb, 256, 0, stream>>>(H, T1, T2, T3, T4, Wt2, b2, H2, n);
  // pool + fc
  k_pool<<<(n + POOL_NODES - 1) / POOL_NODES, 256, 0, stream>>>(H2, batch, g, n);
  k_fc<<<(NG * OC + 255) / 256, 256, 0, stream>>>(g, Wfc, bfc, out, NG, OC);
}